// Round 2
// baseline (3166.733 us; speedup 1.0000x reference)
//
#include <hip/hip_runtime.h>
#include <math.h>

#define SZ 80
#define SS 6400
#define VOX 512000
#define COUT 60
#define EPSF 1e-5f

// halo LDS geometry: [ci(4)][xx(10)][yy(10)][zz(18, padded row 19)]
#define ZROW 19
#define YST  ZROW
#define XST  (10*ZROW)     // 190
#define CIST (10*XST)      // 1900
#define XS_FLOATS (4*CIST) // 7600

// ---------------------------------------------------------------------------
__device__ __forceinline__ float softstep(float t){
    return t > 0.0f ? expf(-1.0f/t) : 0.0f;
}

// Build the 72x4x3x3x3 conv kernel, stored as [k_idx(27)][cin(4)][c(72)].
__global__ void k_build_weights(const float* __restrict__ Wtp, float* __restrict__ wout){
    int idx = blockIdx.x*256 + threadIdx.x;
    if (idx >= 27*4*72) return;
    int c   = idx % 72;
    int cin = (idx/72) & 3;
    int ki  = idx / 288;
    int kz = ki % 3, ky = (ki/3) % 3, kx = ki/9;
    float rx = (float)(kx-1), ry = (float)(ky-1), rz = (float)(kz-1);
    float norm = sqrtf(rx*rx + ry*ry + rz*rz);
    float den = fmaxf(norm, 1e-12f);
    float ux = rx/den, uy = ry/den, uz = rz/den;
    const float C0 = 8.433573069074764f;   // 1.14136 * e^2
    float emb[4];
    #pragma unroll
    for (int r=0;r<4;++r){
        float v = 0.2f*(float)(r+1);
        float d = (norm - v) / 0.2f;
        emb[r] = C0 * softstep(d+1.0f) * softstep(1.0f-d);
    }
    int p; float factor;
    if (c < 28) { p = cin*28 + c; factor = 1.0f; }
    else if (c < 52) {
        int m = (c-28)/3, j = (c-28)%3;
        p = 112 + cin*8 + m;
        float u3[3]; u3[0]=ux; u3[1]=uy; u3[2]=uz;
        factor = 1.7320508075688772f * u3[j];
    } else {
        int m = (c-52)/5, j = (c-52)%5;
        p = 144 + cin*4 + m;
        const float s15 = 3.872983346207417f, s5 = 2.23606797749979f;
        float y2;
        if      (j==0) y2 = s15*ux*uy;
        else if (j==1) y2 = s15*uy*uz;
        else if (j==2) y2 = 0.5f*s5*(2.0f*uz*uz - ux*ux - uy*uy);
        else if (j==3) y2 = s15*ux*uz;
        else           y2 = 0.5f*s15*(ux*ux - uy*uy);
        factor = y2;
    }
    float w = (emb[0]*Wtp[p] + emb[1]*Wtp[160+p] + emb[2]*Wtp[320+p] + emb[3]*Wtp[480+p])
              * (1.0f/5.196152422706632f);          // / K^1.5
    wout[idx] = w * factor * 0.5f;                  // / sqrt(CIN)
}

// ---------------------------------------------------------------------------
__device__ __forceinline__ void stage(const float* __restrict__ xin, int b,
                                      int X0, int Y0, int Z0, float* xs){
    for (int l = threadIdx.x; l < 7200; l += 256){
        int zz  = l % 18;
        int rem = l / 18;
        int yy  = rem % 10;
        int xx  = (rem/10) % 10;
        int ci  = rem/100;
        int gx = X0-1+xx, gy = Y0-1+yy, gz = Z0-1+zz;
        float v = 0.0f;
        if ((unsigned)gx < 80u && (unsigned)gy < 80u && (unsigned)gz < 80u)
            v = xin[(size_t)(b*4+ci)*VOX + gx*SS + gy*SZ + gz];
        xs[ci*CIST + xx*XST + yy*YST + zz] = v;
    }
}

// conv for one 12-channel group; thread owns a z-line of 4 voxels.
// Weight reads are wave-uniform -> compiler emits s_load (SALU path).
__device__ __forceinline__ void conv_group(const float* xs, const float* __restrict__ wg,
                                           int cbase, int lx, int ly, int z0,
                                           float acc[12][4])
{
    #pragma unroll
    for (int c=0;c<12;++c)
        #pragma unroll
        for (int v=0;v<4;++v) acc[c][v]=0.0f;

    for (int ci=0; ci<4; ++ci){
        for (int kx=0; kx<3; ++kx){
            for (int ky=0; ky<3; ++ky){
                const float* xrow = xs + ci*CIST + (lx+kx)*XST + (ly+ky)*YST + z0;
                float xr[6];
                #pragma unroll
                for (int t=0;t<6;++t) xr[t] = xrow[t];
                const float* wrow = wg + (size_t)((kx*3+ky)*3)*288 + ci*72 + cbase;
                #pragma unroll
                for (int c=0;c<12;++c){
                    #pragma unroll
                    for (int kz=0;kz<3;++kz){
                        float w = wrow[(size_t)kz*288 + c];
                        #pragma unroll
                        for (int v=0;v<4;++v)
                            acc[c][v] = fmaf(w, xr[v+kz], acc[c][v]);
                    }
                }
            }
        }
    }
}

// ---------------------------------------------------------------------------
// Pass 1: conv + per-block per-channel {sum, sumsq} partials (144 floats/block)
__global__ __launch_bounds__(256) void k_conv_stats(const float* __restrict__ xin,
        const float* __restrict__ wg, float* __restrict__ partials)
{
    __shared__ float xs[XS_FLOATS];
    __shared__ float red[6][4][24];
    int bid = blockIdx.x;
    int zt = bid%5, yt=(bid/5)%10, xt=(bid/50)%10, b=bid/500;
    int X0=xt*8, Y0=yt*8, Z0=zt*16;
    stage(xin, b, X0, Y0, Z0, xs);
    __syncthreads();

    int tid = threadIdx.x;
    int lz4 = tid&3, ly=(tid>>2)&7, lx=tid>>5;
    int z0 = lz4*4;
    int lane = tid&63, wid = tid>>6;

    for (int g=0; g<6; ++g){
        float acc[12][4];
        conv_group(xs, wg, g*12, lx, ly, z0, acc);
        #pragma unroll
        for (int c=0;c<12;++c){
            float s = acc[c][0]+acc[c][1]+acc[c][2]+acc[c][3];
            float q = acc[c][0]*acc[c][0]+acc[c][1]*acc[c][1]
                    + acc[c][2]*acc[c][2]+acc[c][3]*acc[c][3];
            #pragma unroll
            for (int o=32;o>=1;o>>=1){ s += __shfl_down(s,o); q += __shfl_down(q,o); }
            if (lane==0){ red[g][wid][c*2] = s; red[g][wid][c*2+1] = q; }
        }
    }
    __syncthreads();
    if (tid < 144){
        int g = tid/24, r = tid%24;
        partials[(size_t)bid*144 + tid] =
            red[g][0][r]+red[g][1][r]+red[g][2][r]+red[g][3][r];
    }
}

// ---------------------------------------------------------------------------
// Pass 2: reduce 500 tile-partials per (b,stat) -> stats[b*144+s]
__global__ __launch_bounds__(256) void k_reduce_stats(const float* __restrict__ partials,
                                                      float* __restrict__ stats)
{
    int j = blockIdx.x;            // 0..287
    int b = j / 144, s = j % 144;
    float a = 0.0f;
    for (int t = threadIdx.x; t < 500; t += 256)
        a += partials[(size_t)(b*500+t)*144 + s];
    #pragma unroll
    for (int o=32;o>=1;o>>=1) a += __shfl_down(a,o);
    __shared__ float red[4];
    if ((threadIdx.x & 63)==0) red[threadIdx.x>>6] = a;
    __syncthreads();
    if (threadIdx.x==0) stats[j] = red[0]+red[1]+red[2]+red[3];
}

// ---------------------------------------------------------------------------
// Pass 3: conv again + instance-norm + gate + write (fully unrolled groups so
// gate[] indexing stays compile-time -> registers, not scratch)
__global__ __launch_bounds__(256) void k_conv_finish(const float* __restrict__ xin,
        const float* __restrict__ wg, const float* __restrict__ stats,
        const float* __restrict__ bnw, const float* __restrict__ bnb,
        float* __restrict__ out)
{
    __shared__ float xs[XS_FLOATS];
    int bid = blockIdx.x;
    int zt = bid%5, yt=(bid/5)%10, xt=(bid/50)%10, b=bid/500;
    int X0=xt*8, Y0=yt*8, Z0=zt*16;
    stage(xin, b, X0, Y0, Z0, xs);
    __syncthreads();

    int tid = threadIdx.x;
    int lz4 = tid&3, ly=(tid>>2)&7, lx=tid>>5;
    int z0 = lz4*4;
    int gx = X0+lx, gy = Y0+ly, gzb = Z0+z0;

    const float* st = stats + b*144;
    const float invN = 1.0f/512000.0f;
    float* op = out + (size_t)b*COUT*VOX + gx*SS + gy*SZ + gzb;

    float gate[12][4];

    #pragma unroll
    for (int g=0; g<6; ++g){
        float acc[12][4];
        conv_group(xs, wg, g*12, lx, ly, z0, acc);
        #pragma unroll
        for (int c12=0;c12<12;++c12){
            const int c = g*12 + c12;
            if (c < 28){
                float mean = st[c*2]*invN;
                float var  = fmaxf(st[c*2+1]*invN - mean*mean, 0.0f);
                float istd = 1.0f/sqrtf(var + EPSF);
                float w = bnw[c], bb = bnb[c];
                if (c < 16){
                    float4 o;
                    o.x = 1.41421356237f*fmaxf((acc[c12][0]-mean)*istd*w+bb, 0.0f);
                    o.y = 1.41421356237f*fmaxf((acc[c12][1]-mean)*istd*w+bb, 0.0f);
                    o.z = 1.41421356237f*fmaxf((acc[c12][2]-mean)*istd*w+bb, 0.0f);
                    o.w = 1.41421356237f*fmaxf((acc[c12][3]-mean)*istd*w+bb, 0.0f);
                    *reinterpret_cast<float4*>(op + (size_t)c*VOX) = o;
                } else {
                    #pragma unroll
                    for (int v=0;v<4;++v){
                        float sn = (acc[c12][v]-mean)*istd*w + bb;
                        gate[c-16][v] = 1.8464f/(1.0f + expf(-sn));
                    }
                }
            } else if (c < 52){
                const int m = (c-28)/3;
                float n1 = (st[(28+3*m)*2+1]+st[(29+3*m)*2+1]+st[(30+3*m)*2+1])
                           * (1.0f/(3.0f*512000.0f));
                float sc = (1.0f/sqrtf(n1+EPSF)) * bnw[28+m];
                float4 o;
                o.x = acc[c12][0]*sc*gate[m][0];
                o.y = acc[c12][1]*sc*gate[m][1];
                o.z = acc[c12][2]*sc*gate[m][2];
                o.w = acc[c12][3]*sc*gate[m][3];
                *reinterpret_cast<float4*>(op + (size_t)(16 + (c-28))*VOX) = o;
            } else {
                const int m = (c-52)/5;
                float n2 = (st[(52+5*m)*2+1]+st[(53+5*m)*2+1]+st[(54+5*m)*2+1]
                          + st[(55+5*m)*2+1]+st[(56+5*m)*2+1])
                           * (1.0f/(5.0f*512000.0f));
                float sc = (1.0f/sqrtf(n2+EPSF)) * bnw[36+m];
                float4 o;
                o.x = acc[c12][0]*sc*gate[8+m][0];
                o.y = acc[c12][1]*sc*gate[8+m][1];
                o.z = acc[c12][2]*sc*gate[8+m][2];
                o.w = acc[c12][3]*sc*gate[8+m][3];
                *reinterpret_cast<float4*>(op + (size_t)(40 + (c-52))*VOX) = o;
            }
        }
    }
}

// ---------------------------------------------------------------------------
extern "C" void kernel_launch(void* const* d_in, const int* in_sizes, int n_in,
                              void* d_out, int out_size, void* d_ws, size_t ws_size,
                              hipStream_t stream)
{
    const float* x   = (const float*)d_in[0];
    const float* Wtp = (const float*)d_in[1];
    const float* bnw = (const float*)d_in[2];
    const float* bnb = (const float*)d_in[3];
    float* ws       = (float*)d_ws;
    float* wgt      = ws;                    // 7776 floats
    float* partials = ws + 8192;             // 1000*144 = 144000 floats
    float* stats    = ws + 8192 + 144000;    // 288 floats

    k_build_weights<<<31, 256, 0, stream>>>(Wtp, wgt);
    k_conv_stats  <<<1000, 256, 0, stream>>>(x, wgt, partials);
    k_reduce_stats<<<288, 256, 0, stream>>>(partials, stats);
    k_conv_finish <<<1000, 256, 0, stream>>>(x, wgt, stats, bnw, bnb, (float*)d_out);
}

// Round 3
// 418.381 us; speedup vs baseline: 7.5690x; 7.5690x over previous
//
#include <hip/hip_runtime.h>
#include <math.h>

#define SZ 80
#define SS 6400
#define VOX 512000
#define COUT 60
#define EPSF 1e-5f

// halo LDS geometry: [ci(4)][xx(10)][yy(10)][zz(18, padded to 20 for 16B alignment)]
#define ZROW 20
#define YST  ZROW          // 20
#define XST  (10*ZROW)     // 200
#define CIST (10*XST)      // 2000
#define XS_FLOATS (4*CIST) // 8000 = 32KB

// ---------------------------------------------------------------------------
__device__ __forceinline__ float softstep(float t){
    return t > 0.0f ? expf(-1.0f/t) : 0.0f;
}

// Build the 72x4x3x3x3 conv kernel, stored as [k_idx(27)][cin(4)][c(72)].
__global__ void k_build_weights(const float* __restrict__ Wtp, float* __restrict__ wout){
    int idx = blockIdx.x*256 + threadIdx.x;
    if (idx >= 27*4*72) return;
    int c   = idx % 72;
    int cin = (idx/72) & 3;
    int ki  = idx / 288;
    int kz = ki % 3, ky = (ki/3) % 3, kx = ki/9;
    float rx = (float)(kx-1), ry = (float)(ky-1), rz = (float)(kz-1);
    float norm = sqrtf(rx*rx + ry*ry + rz*rz);
    float den = fmaxf(norm, 1e-12f);
    float ux = rx/den, uy = ry/den, uz = rz/den;
    const float C0 = 8.433573069074764f;   // 1.14136 * e^2
    float emb[4];
    #pragma unroll
    for (int r=0;r<4;++r){
        float v = 0.2f*(float)(r+1);
        float d = (norm - v) / 0.2f;
        emb[r] = C0 * softstep(d+1.0f) * softstep(1.0f-d);
    }
    int p; float factor;
    if (c < 28) { p = cin*28 + c; factor = 1.0f; }
    else if (c < 52) {
        int m = (c-28)/3, j = (c-28)%3;
        p = 112 + cin*8 + m;
        float u3[3]; u3[0]=ux; u3[1]=uy; u3[2]=uz;
        factor = 1.7320508075688772f * u3[j];
    } else {
        int m = (c-52)/5, j = (c-52)%5;
        p = 144 + cin*4 + m;
        const float s15 = 3.872983346207417f, s5 = 2.23606797749979f;
        float y2;
        if      (j==0) y2 = s15*ux*uy;
        else if (j==1) y2 = s15*uy*uz;
        else if (j==2) y2 = 0.5f*s5*(2.0f*uz*uz - ux*ux - uy*uy);
        else if (j==3) y2 = s15*ux*uz;
        else           y2 = 0.5f*s15*(ux*ux - uy*uy);
        factor = y2;
    }
    float w = (emb[0]*Wtp[p] + emb[1]*Wtp[160+p] + emb[2]*Wtp[320+p] + emb[3]*Wtp[480+p])
              * (1.0f/5.196152422706632f);          // / K^1.5
    wout[idx] = w * factor * 0.5f;                  // / sqrt(CIN)
}

// ---------------------------------------------------------------------------
__device__ __forceinline__ void stage(const float* __restrict__ xin, int b,
                                      int X0, int Y0, int Z0,
                                      float* xs, float* wl,
                                      const float* __restrict__ wg){
    for (int l = threadIdx.x; l < 7776; l += 256) wl[l] = wg[l];
    for (int l = threadIdx.x; l < 7200; l += 256){
        int zz  = l % 18;
        int rem = l / 18;
        int yy  = rem % 10;
        int xx  = (rem/10) % 10;
        int ci  = rem/100;
        int gx = X0-1+xx, gy = Y0-1+yy, gz = Z0-1+zz;
        float v = 0.0f;
        if ((unsigned)gx < 80u && (unsigned)gy < 80u && (unsigned)gz < 80u)
            v = xin[(size_t)(b*4+ci)*VOX + gx*SS + gy*SZ + gz];
        xs[ci*CIST + xx*XST + yy*YST + zz] = v;
    }
}

// conv for one 12-channel group; thread owns a z-line of 4 voxels.
// Weights come from LDS via broadcast (uniform-address) ds_read_b128.
// Inner loops rolled (unroll 1) to keep code ~1.3KB; the 144-FMA body gives ILP.
__device__ __forceinline__ void conv_group(const float* xs, const float* wl,
                                           int cbase, int lx, int ly, int z0,
                                           float acc[12][4])
{
    #pragma unroll
    for (int c=0;c<12;++c){ acc[c][0]=0.f; acc[c][1]=0.f; acc[c][2]=0.f; acc[c][3]=0.f; }

    #pragma unroll 1
    for (int ci=0; ci<4; ++ci){
      #pragma unroll 1
      for (int kx=0; kx<3; ++kx){
        #pragma unroll 1
        for (int ky=0; ky<3; ++ky){
            const float* xrow = xs + ci*CIST + (lx+kx)*XST + (ly+ky)*YST + z0;
            float4 xa = *reinterpret_cast<const float4*>(xrow);
            float2 xb = *reinterpret_cast<const float2*>(xrow+4);
            float xr[6];
            xr[0]=xa.x; xr[1]=xa.y; xr[2]=xa.z; xr[3]=xa.w; xr[4]=xb.x; xr[5]=xb.y;
            const float* wbase = wl + ((kx*3+ky)*3)*288 + ci*72 + cbase;
            #pragma unroll
            for (int kz=0;kz<3;++kz){
                float w12[12];
                *reinterpret_cast<float4*>(w12+0) = *reinterpret_cast<const float4*>(wbase + kz*288 + 0);
                *reinterpret_cast<float4*>(w12+4) = *reinterpret_cast<const float4*>(wbase + kz*288 + 4);
                *reinterpret_cast<float4*>(w12+8) = *reinterpret_cast<const float4*>(wbase + kz*288 + 8);
                #pragma unroll
                for (int c=0;c<12;++c)
                    #pragma unroll
                    for (int v=0;v<4;++v)
                        acc[c][v] = fmaf(w12[c], xr[v+kz], acc[c][v]);
            }
        }
      }
    }
}

// ---------------------------------------------------------------------------
// Pass 1: conv + per-channel {sum,sumsq} partials; optionally writes h (path A).
__global__ __launch_bounds__(256) void k_conv_stats(const float* __restrict__ xin,
        const float* __restrict__ wg, float* __restrict__ partials,
        float* __restrict__ h)
{
    __shared__ float xs[XS_FLOATS];
    __shared__ float wl[7776];
    __shared__ float red[6][4][24];
    int bid = blockIdx.x;
    int zt = bid%5, yt=(bid/5)%10, xt=(bid/50)%10, b=bid/500;
    int X0=xt*8, Y0=yt*8, Z0=zt*16;
    stage(xin, b, X0, Y0, Z0, xs, wl, wg);
    __syncthreads();

    int tid = threadIdx.x;
    int lz4 = tid&3, ly=(tid>>2)&7, lx=tid>>5;
    int z0 = lz4*4;
    int lane = tid&63, wid = tid>>6;
    int vox = (X0+lx)*SS + (Y0+ly)*SZ + (Z0+z0);

    #pragma unroll 1
    for (int g=0; g<6; ++g){
        float acc[12][4];
        conv_group(xs, wl, g*12, lx, ly, z0, acc);
        if (h){
            #pragma unroll
            for (int c=0;c<12;++c){
                float4 o; o.x=acc[c][0]; o.y=acc[c][1]; o.z=acc[c][2]; o.w=acc[c][3];
                *reinterpret_cast<float4*>(h + (size_t)(b*72 + g*12 + c)*VOX + vox) = o;
            }
        }
        #pragma unroll
        for (int c=0;c<12;++c){
            float s = acc[c][0]+acc[c][1]+acc[c][2]+acc[c][3];
            float q = acc[c][0]*acc[c][0]+acc[c][1]*acc[c][1]
                    + acc[c][2]*acc[c][2]+acc[c][3]*acc[c][3];
            #pragma unroll
            for (int o=32;o>=1;o>>=1){ s += __shfl_down(s,o); q += __shfl_down(q,o); }
            if (lane==0){ red[g][wid][c*2] = s; red[g][wid][c*2+1] = q; }
        }
    }
    __syncthreads();
    if (tid < 144){
        int g = tid/24, r = tid%24;
        partials[(size_t)bid*144 + tid] =
            red[g][0][r]+red[g][1][r]+red[g][2][r]+red[g][3][r];
    }
}

// ---------------------------------------------------------------------------
__global__ __launch_bounds__(256) void k_reduce_stats(const float* __restrict__ partials,
                                                      float* __restrict__ stats)
{
    int j = blockIdx.x;            // 0..287
    int b = j / 144, s = j % 144;
    float a = 0.0f;
    for (int t = threadIdx.x; t < 500; t += 256)
        a += partials[(size_t)(b*500+t)*144 + s];
    #pragma unroll
    for (int o=32;o>=1;o>>=1) a += __shfl_down(a,o);
    __shared__ float red[4];
    if ((threadIdx.x & 63)==0) red[threadIdx.x>>6] = a;
    __syncthreads();
    if (threadIdx.x==0) stats[j] = red[0]+red[1]+red[2]+red[3];
}

// ---------------------------------------------------------------------------
// Path A pass 3: stream h -> normalize+gate -> out.  Memory-bound.
__global__ __launch_bounds__(256) void k_norm_from_h(const float* __restrict__ h,
        const float* __restrict__ stats, const float* __restrict__ bnw,
        const float* __restrict__ bnb, float* __restrict__ out)
{
    int idx = blockIdx.x*256 + threadIdx.x;     // 256000 threads
    int b   = idx / 128000;
    int off = (idx % 128000) * 4;
    const float* hp = h   + (size_t)b*72*VOX + off;
    float*       op = out + (size_t)b*COUT*VOX + off;
    const float* st = stats + b*144;
    const float invN = 1.0f/512000.0f;

    float gate[12][4];
    #pragma unroll
    for (int m=0;m<12;++m){
        int c = 16+m;
        float4 hv = *reinterpret_cast<const float4*>(hp + (size_t)c*VOX);
        float mean = st[c*2]*invN;
        float var  = fmaxf(st[c*2+1]*invN - mean*mean, 0.0f);
        float sw   = (1.0f/sqrtf(var+EPSF)) * bnw[c];
        float bb   = bnb[c];
        gate[m][0] = 1.8464f/(1.0f+expf(-((hv.x-mean)*sw+bb)));
        gate[m][1] = 1.8464f/(1.0f+expf(-((hv.y-mean)*sw+bb)));
        gate[m][2] = 1.8464f/(1.0f+expf(-((hv.z-mean)*sw+bb)));
        gate[m][3] = 1.8464f/(1.0f+expf(-((hv.w-mean)*sw+bb)));
    }
    #pragma unroll
    for (int c=0;c<16;++c){
        float4 hv = *reinterpret_cast<const float4*>(hp + (size_t)c*VOX);
        float mean = st[c*2]*invN;
        float var  = fmaxf(st[c*2+1]*invN - mean*mean, 0.0f);
        float sw   = (1.0f/sqrtf(var+EPSF)) * bnw[c];
        float bb   = bnb[c];
        float4 o;
        o.x = 1.41421356237f*fmaxf((hv.x-mean)*sw+bb, 0.0f);
        o.y = 1.41421356237f*fmaxf((hv.y-mean)*sw+bb, 0.0f);
        o.z = 1.41421356237f*fmaxf((hv.z-mean)*sw+bb, 0.0f);
        o.w = 1.41421356237f*fmaxf((hv.w-mean)*sw+bb, 0.0f);
        *reinterpret_cast<float4*>(op + (size_t)c*VOX) = o;
    }
    #pragma unroll
    for (int m=0;m<8;++m){
        float n1 = (st[(28+3*m)*2+1]+st[(29+3*m)*2+1]+st[(30+3*m)*2+1])
                   * (1.0f/(3.0f*512000.0f));
        float sc = (1.0f/sqrtf(n1+EPSF)) * bnw[28+m];
        #pragma unroll
        for (int j=0;j<3;++j){
            float4 hv = *reinterpret_cast<const float4*>(hp + (size_t)(28+3*m+j)*VOX);
            float4 o;
            o.x = hv.x*sc*gate[m][0]; o.y = hv.y*sc*gate[m][1];
            o.z = hv.z*sc*gate[m][2]; o.w = hv.w*sc*gate[m][3];
            *reinterpret_cast<float4*>(op + (size_t)(16+3*m+j)*VOX) = o;
        }
    }
    #pragma unroll
    for (int m=0;m<4;++m){
        float n2 = (st[(52+5*m)*2+1]+st[(53+5*m)*2+1]+st[(54+5*m)*2+1]
                  + st[(55+5*m)*2+1]+st[(56+5*m)*2+1]) * (1.0f/(5.0f*512000.0f));
        float sc = (1.0f/sqrtf(n2+EPSF)) * bnw[36+m];
        #pragma unroll
        for (int j=0;j<5;++j){
            float4 hv = *reinterpret_cast<const float4*>(hp + (size_t)(52+5*m+j)*VOX);
            float4 o;
            o.x = hv.x*sc*gate[8+m][0]; o.y = hv.y*sc*gate[8+m][1];
            o.z = hv.z*sc*gate[8+m][2]; o.w = hv.w*sc*gate[8+m][3];
            *reinterpret_cast<float4*>(op + (size_t)(40+5*m+j)*VOX) = o;
        }
    }
}

// ---------------------------------------------------------------------------
// Path B pass 3: recompute conv + normalize + gate + write.
__global__ __launch_bounds__(256) void k_conv_finish(const float* __restrict__ xin,
        const float* __restrict__ wg, const float* __restrict__ stats,
        const float* __restrict__ bnw, const float* __restrict__ bnb,
        float* __restrict__ out)
{
    __shared__ float xs[XS_FLOATS];
    __shared__ float wl[7776];
    int bid = blockIdx.x;
    int zt = bid%5, yt=(bid/5)%10, xt=(bid/50)%10, b=bid/500;
    int X0=xt*8, Y0=yt*8, Z0=zt*16;
    stage(xin, b, X0, Y0, Z0, xs, wl, wg);
    __syncthreads();

    int tid = threadIdx.x;
    int lz4 = tid&3, ly=(tid>>2)&7, lx=tid>>5;
    int z0 = lz4*4;
    const float* st = stats + b*144;
    const float invN = 1.0f/512000.0f;
    float* op = out + (size_t)b*COUT*VOX + (X0+lx)*SS + (Y0+ly)*SZ + (Z0+z0);

    float gate[12][4];
    #pragma unroll
    for (int g=0; g<6; ++g){
        float acc[12][4];
        conv_group(xs, wl, g*12, lx, ly, z0, acc);
        #pragma unroll
        for (int c12=0;c12<12;++c12){
            const int c = g*12 + c12;
            if (c < 28){
                float mean = st[c*2]*invN;
                float var  = fmaxf(st[c*2+1]*invN - mean*mean, 0.0f);
                float sw   = (1.0f/sqrtf(var+EPSF)) * bnw[c];
                float bb   = bnb[c];
                if (c < 16){
                    float4 o;
                    o.x = 1.41421356237f*fmaxf((acc[c12][0]-mean)*sw+bb, 0.0f);
                    o.y = 1.41421356237f*fmaxf((acc[c12][1]-mean)*sw+bb, 0.0f);
                    o.z = 1.41421356237f*fmaxf((acc[c12][2]-mean)*sw+bb, 0.0f);
                    o.w = 1.41421356237f*fmaxf((acc[c12][3]-mean)*sw+bb, 0.0f);
                    *reinterpret_cast<float4*>(op + (size_t)c*VOX) = o;
                } else {
                    #pragma unroll
                    for (int v=0;v<4;++v)
                        gate[c-16][v] = 1.8464f/(1.0f + expf(-((acc[c12][v]-mean)*sw+bb)));
                }
            } else if (c < 52){
                const int m = (c-28)/3;
                float n1 = (st[(28+3*m)*2+1]+st[(29+3*m)*2+1]+st[(30+3*m)*2+1])
                           * (1.0f/(3.0f*512000.0f));
                float sc = (1.0f/sqrtf(n1+EPSF)) * bnw[28+m];
                float4 o;
                o.x = acc[c12][0]*sc*gate[m][0]; o.y = acc[c12][1]*sc*gate[m][1];
                o.z = acc[c12][2]*sc*gate[m][2]; o.w = acc[c12][3]*sc*gate[m][3];
                *reinterpret_cast<float4*>(op + (size_t)(16 + (c-28))*VOX) = o;
            } else {
                const int m = (c-52)/5;
                float n2 = (st[(52+5*m)*2+1]+st[(53+5*m)*2+1]+st[(54+5*m)*2+1]
                          + st[(55+5*m)*2+1]+st[(56+5*m)*2+1]) * (1.0f/(5.0f*512000.0f));
                float sc = (1.0f/sqrtf(n2+EPSF)) * bnw[36+m];
                float4 o;
                o.x = acc[c12][0]*sc*gate[8+m][0]; o.y = acc[c12][1]*sc*gate[8+m][1];
                o.z = acc[c12][2]*sc*gate[8+m][2]; o.w = acc[c12][3]*sc*gate[8+m][3];
                *reinterpret_cast<float4*>(op + (size_t)(40 + (c-52))*VOX) = o;
            }
        }
    }
}

// ---------------------------------------------------------------------------
extern "C" void kernel_launch(void* const* d_in, const int* in_sizes, int n_in,
                              void* d_out, int out_size, void* d_ws, size_t ws_size,
                              hipStream_t stream)
{
    const float* x   = (const float*)d_in[0];
    const float* Wtp = (const float*)d_in[1];
    const float* bnw = (const float*)d_in[2];
    const float* bnb = (const float*)d_in[3];
    float* ws       = (float*)d_ws;
    float* wgt      = ws;                    // 7776 floats
    float* partials = ws + 8192;             // 1000*144 = 144000 floats
    float* stats    = ws + 8192 + 144000;    // 288 floats
    float* h        = ws + 160000;           // 2*72*512000 = 73,728,000 floats

    const size_t needH = (160000ull + 73728000ull) * 4ull;
    const bool useH = ws_size >= needH;

    k_build_weights<<<31, 256, 0, stream>>>(Wtp, wgt);
    k_conv_stats  <<<1000, 256, 0, stream>>>(x, wgt, partials, useH ? h : nullptr);
    k_reduce_stats<<<288, 256, 0, stream>>>(partials, stats);
    if (useH)
        k_norm_from_h<<<1000, 256, 0, stream>>>(h, stats, bnw, bnb, (float*)d_out);
    else
        k_conv_finish<<<1000, 256, 0, stream>>>(x, wgt, stats, bnw, bnb, (float*)d_out);
}

// Round 4
// 400.560 us; speedup vs baseline: 7.9058x; 1.0445x over previous
//
#include <hip/hip_runtime.h>
#include <math.h>

#define SZ 80
#define SS 6400
#define VOX 512000
#define COUT 60
#define EPSF 1e-5f

// halo LDS geometry: [ci(4)][xx(10)][yy(10)][zz(18, padded to 20 for 16B alignment)]
#define ZROW 20
#define YST  ZROW          // 20
#define XST  (10*ZROW)     // 200
#define CIST (10*XST)      // 2000
#define XS_FLOATS (4*CIST) // 8000 = 32KB

// per-group weight slice: [tap(27)][ci(4)][c12(12)] = 1296 floats = 5.2KB
#define WG_FLOATS 1296

// ---------------------------------------------------------------------------
__device__ __forceinline__ float softstep(float t){
    return t > 0.0f ? expf(-1.0f/t) : 0.0f;
}

// Build conv weights, laid out per channel-group:
//   wout[g*1296 + ki*48 + cin*12 + c12],  ki = kx*9+ky*3+kz, g = c/12
__global__ void k_build_weights(const float* __restrict__ Wtp, float* __restrict__ wout){
    int idx = blockIdx.x*256 + threadIdx.x;
    if (idx >= 27*4*72) return;
    int c   = idx % 72;
    int cin = (idx/72) & 3;
    int ki  = idx / 288;
    int kz = ki % 3, ky = (ki/3) % 3, kx = ki/9;
    float rx = (float)(kx-1), ry = (float)(ky-1), rz = (float)(kz-1);
    float norm = sqrtf(rx*rx + ry*ry + rz*rz);
    float den = fmaxf(norm, 1e-12f);
    float ux = rx/den, uy = ry/den, uz = rz/den;
    const float C0 = 8.433573069074764f;   // 1.14136 * e^2
    float emb[4];
    #pragma unroll
    for (int r=0;r<4;++r){
        float v = 0.2f*(float)(r+1);
        float d = (norm - v) / 0.2f;
        emb[r] = C0 * softstep(d+1.0f) * softstep(1.0f-d);
    }
    int p; float factor;
    if (c < 28) { p = cin*28 + c; factor = 1.0f; }
    else if (c < 52) {
        int m = (c-28)/3, j = (c-28)%3;
        p = 112 + cin*8 + m;
        float u3[3]; u3[0]=ux; u3[1]=uy; u3[2]=uz;
        factor = 1.7320508075688772f * u3[j];
    } else {
        int m = (c-52)/5, j = (c-52)%5;
        p = 144 + cin*4 + m;
        const float s15 = 3.872983346207417f, s5 = 2.23606797749979f;
        float y2;
        if      (j==0) y2 = s15*ux*uy;
        else if (j==1) y2 = s15*uy*uz;
        else if (j==2) y2 = 0.5f*s5*(2.0f*uz*uz - ux*ux - uy*uy);
        else if (j==3) y2 = s15*ux*uz;
        else           y2 = 0.5f*s15*(ux*ux - uy*uy);
        factor = y2;
    }
    float w = (emb[0]*Wtp[p] + emb[1]*Wtp[160+p] + emb[2]*Wtp[320+p] + emb[3]*Wtp[480+p])
              * (1.0f/5.196152422706632f);          // / K^1.5
    int g = c/12, c12 = c%12;
    wout[g*WG_FLOATS + ki*48 + cin*12 + c12] = w * factor * 0.5f;   // / sqrt(CIN)
}

// ---------------------------------------------------------------------------
__device__ __forceinline__ void stage_x(const float* __restrict__ xin, int b,
                                        int X0, int Y0, int Z0, float* xs){
    for (int l = threadIdx.x; l < 7200; l += 256){
        int zz  = l % 18;
        int rem = l / 18;
        int yy  = rem % 10;
        int xx  = (rem/10) % 10;
        int ci  = rem/100;
        int gx = X0-1+xx, gy = Y0-1+yy, gz = Z0-1+zz;
        float v = 0.0f;
        if ((unsigned)gx < 80u && (unsigned)gy < 80u && (unsigned)gz < 80u)
            v = xin[(size_t)(b*4+ci)*VOX + gx*SS + gy*SZ + gz];
        xs[ci*CIST + xx*XST + yy*YST + zz] = v;
    }
}

// conv for one 12-channel group; thread owns a z-line of 4 voxels.
// wl = this group's 1296 weights: [tap(27)][ci(4)][c12(12)].
__device__ __forceinline__ void conv_group(const float* xs, const float* wl,
                                           int lx, int ly, int z0,
                                           float acc[12][4])
{
    #pragma unroll
    for (int c=0;c<12;++c){ acc[c][0]=0.f; acc[c][1]=0.f; acc[c][2]=0.f; acc[c][3]=0.f; }

    #pragma unroll 1
    for (int ci=0; ci<4; ++ci){
      #pragma unroll 1
      for (int kx=0; kx<3; ++kx){
        #pragma unroll 1
        for (int ky=0; ky<3; ++ky){
            const float* xrow = xs + ci*CIST + (lx+kx)*XST + (ly+ky)*YST + z0;
            float4 xa = *reinterpret_cast<const float4*>(xrow);
            float2 xb = *reinterpret_cast<const float2*>(xrow+4);
            float xr[6];
            xr[0]=xa.x; xr[1]=xa.y; xr[2]=xa.z; xr[3]=xa.w; xr[4]=xb.x; xr[5]=xb.y;
            const float* wbase = wl + ((kx*3+ky)*3)*48 + ci*12;
            #pragma unroll
            for (int kz=0;kz<3;++kz){
                float w12[12];
                *reinterpret_cast<float4*>(w12+0) = *reinterpret_cast<const float4*>(wbase + kz*48 + 0);
                *reinterpret_cast<float4*>(w12+4) = *reinterpret_cast<const float4*>(wbase + kz*48 + 4);
                *reinterpret_cast<float4*>(w12+8) = *reinterpret_cast<const float4*>(wbase + kz*48 + 8);
                #pragma unroll
                for (int c=0;c<12;++c)
                    #pragma unroll
                    for (int v=0;v<4;++v)
                        acc[c][v] = fmaf(w12[c], xr[v+kz], acc[c][v]);
            }
        }
      }
    }
}

// ---------------------------------------------------------------------------
// Pass 1: conv + per-channel {sum,sumsq} partials; optionally writes h (path A).
__global__ __launch_bounds__(256) void k_conv_stats(const float* __restrict__ xin,
        const float* __restrict__ wg, float* __restrict__ partials,
        float* __restrict__ h)
{
    __shared__ float xs[XS_FLOATS];
    __shared__ float wl[WG_FLOATS];
    __shared__ float red[6][4][24];
    int bid = blockIdx.x;
    int zt = bid%5, yt=(bid/5)%10, xt=(bid/50)%10, b=bid/500;
    int X0=xt*8, Y0=yt*8, Z0=zt*16;
    stage_x(xin, b, X0, Y0, Z0, xs);

    int tid = threadIdx.x;
    int lz4 = tid&3, ly=(tid>>2)&7, lx=tid>>5;
    int z0 = lz4*4;
    int lane = tid&63, wid = tid>>6;
    int vox = (X0+lx)*SS + (Y0+ly)*SZ + (Z0+z0);

    #pragma unroll 1
    for (int g=0; g<6; ++g){
        __syncthreads();                       // xs staged (g=0) / wl free (g>0)
        for (int l = tid; l < WG_FLOATS; l += 256) wl[l] = wg[g*WG_FLOATS + l];
        __syncthreads();

        float acc[12][4];
        conv_group(xs, wl, lx, ly, z0, acc);
        if (h){
            #pragma unroll
            for (int c=0;c<12;++c){
                float4 o; o.x=acc[c][0]; o.y=acc[c][1]; o.z=acc[c][2]; o.w=acc[c][3];
                *reinterpret_cast<float4*>(h + (size_t)(b*72 + g*12 + c)*VOX + vox) = o;
            }
        }
        #pragma unroll
        for (int c=0;c<12;++c){
            float s = acc[c][0]+acc[c][1]+acc[c][2]+acc[c][3];
            float q = acc[c][0]*acc[c][0]+acc[c][1]*acc[c][1]
                    + acc[c][2]*acc[c][2]+acc[c][3]*acc[c][3];
            #pragma unroll
            for (int o=32;o>=1;o>>=1){ s += __shfl_down(s,o); q += __shfl_down(q,o); }
            if (lane==0){ red[g][wid][c*2] = s; red[g][wid][c*2+1] = q; }
        }
    }
    __syncthreads();
    if (tid < 144){
        int g = tid/24, r = tid%24;
        partials[(size_t)bid*144 + tid] =
            red[g][0][r]+red[g][1][r]+red[g][2][r]+red[g][3][r];
    }
}

// ---------------------------------------------------------------------------
__global__ __launch_bounds__(256) void k_reduce_stats(const float* __restrict__ partials,
                                                      float* __restrict__ stats)
{
    int j = blockIdx.x;            // 0..287
    int b = j / 144, s = j % 144;
    float a = 0.0f;
    for (int t = threadIdx.x; t < 500; t += 256)
        a += partials[(size_t)(b*500+t)*144 + s];
    #pragma unroll
    for (int o=32;o>=1;o>>=1) a += __shfl_down(a,o);
    __shared__ float red[4];
    if ((threadIdx.x & 63)==0) red[threadIdx.x>>6] = a;
    __syncthreads();
    if (threadIdx.x==0) stats[j] = red[0]+red[1]+red[2]+red[3];
}

// ---------------------------------------------------------------------------
// Path A pass 3: stream h -> normalize+gate -> out.  Memory-bound.
__global__ __launch_bounds__(256) void k_norm_from_h(const float* __restrict__ h,
        const float* __restrict__ stats, const float* __restrict__ bnw,
        const float* __restrict__ bnb, float* __restrict__ out)
{
    int idx = blockIdx.x*256 + threadIdx.x;     // 256000 threads
    int b   = idx / 128000;
    int off = (idx % 128000) * 4;
    const float* hp = h   + (size_t)b*72*VOX + off;
    float*       op = out + (size_t)b*COUT*VOX + off;
    const float* st = stats + b*144;
    const float invN = 1.0f/512000.0f;

    float gate[12][4];
    #pragma unroll
    for (int m=0;m<12;++m){
        int c = 16+m;
        float4 hv = *reinterpret_cast<const float4*>(hp + (size_t)c*VOX);
        float mean = st[c*2]*invN;
        float var  = fmaxf(st[c*2+1]*invN - mean*mean, 0.0f);
        float sw   = (1.0f/sqrtf(var+EPSF)) * bnw[c];
        float bb   = bnb[c];
        gate[m][0] = 1.8464f/(1.0f+expf(-((hv.x-mean)*sw+bb)));
        gate[m][1] = 1.8464f/(1.0f+expf(-((hv.y-mean)*sw+bb)));
        gate[m][2] = 1.8464f/(1.0f+expf(-((hv.z-mean)*sw+bb)));
        gate[m][3] = 1.8464f/(1.0f+expf(-((hv.w-mean)*sw+bb)));
    }
    #pragma unroll
    for (int c=0;c<16;++c){
        float4 hv = *reinterpret_cast<const float4*>(hp + (size_t)c*VOX);
        float mean = st[c*2]*invN;
        float var  = fmaxf(st[c*2+1]*invN - mean*mean, 0.0f);
        float sw   = (1.0f/sqrtf(var+EPSF)) * bnw[c];
        float bb   = bnb[c];
        float4 o;
        o.x = 1.41421356237f*fmaxf((hv.x-mean)*sw+bb, 0.0f);
        o.y = 1.41421356237f*fmaxf((hv.y-mean)*sw+bb, 0.0f);
        o.z = 1.41421356237f*fmaxf((hv.z-mean)*sw+bb, 0.0f);
        o.w = 1.41421356237f*fmaxf((hv.w-mean)*sw+bb, 0.0f);
        *reinterpret_cast<float4*>(op + (size_t)c*VOX) = o;
    }
    #pragma unroll
    for (int m=0;m<8;++m){
        float n1 = (st[(28+3*m)*2+1]+st[(29+3*m)*2+1]+st[(30+3*m)*2+1])
                   * (1.0f/(3.0f*512000.0f));
        float sc = (1.0f/sqrtf(n1+EPSF)) * bnw[28+m];
        #pragma unroll
        for (int j=0;j<3;++j){
            float4 hv = *reinterpret_cast<const float4*>(hp + (size_t)(28+3*m+j)*VOX);
            float4 o;
            o.x = hv.x*sc*gate[m][0]; o.y = hv.y*sc*gate[m][1];
            o.z = hv.z*sc*gate[m][2]; o.w = hv.w*sc*gate[m][3];
            *reinterpret_cast<float4*>(op + (size_t)(16+3*m+j)*VOX) = o;
        }
    }
    #pragma unroll
    for (int m=0;m<4;++m){
        float n2 = (st[(52+5*m)*2+1]+st[(53+5*m)*2+1]+st[(54+5*m)*2+1]
                  + st[(55+5*m)*2+1]+st[(56+5*m)*2+1]) * (1.0f/(5.0f*512000.0f));
        float sc = (1.0f/sqrtf(n2+EPSF)) * bnw[36+m];
        #pragma unroll
        for (int j=0;j<5;++j){
            float4 hv = *reinterpret_cast<const float4*>(hp + (size_t)(52+5*m+j)*VOX);
            float4 o;
            o.x = hv.x*sc*gate[8+m][0]; o.y = hv.y*sc*gate[8+m][1];
            o.z = hv.z*sc*gate[8+m][2]; o.w = hv.w*sc*gate[8+m][3];
            *reinterpret_cast<float4*>(op + (size_t)(40+5*m+j)*VOX) = o;
        }
    }
}

// ---------------------------------------------------------------------------
// Path B pass 3: recompute conv + normalize + gate + write.
__global__ __launch_bounds__(256) void k_conv_finish(const float* __restrict__ xin,
        const float* __restrict__ wg, const float* __restrict__ stats,
        const float* __restrict__ bnw, const float* __restrict__ bnb,
        float* __restrict__ out)
{
    __shared__ float xs[XS_FLOATS];
    __shared__ float wl[WG_FLOATS];
    int bid = blockIdx.x;
    int zt = bid%5, yt=(bid/5)%10, xt=(bid/50)%10, b=bid/500;
    int X0=xt*8, Y0=yt*8, Z0=zt*16;
    stage_x(xin, b, X0, Y0, Z0, xs);

    int tid = threadIdx.x;
    int lz4 = tid&3, ly=(tid>>2)&7, lx=tid>>5;
    int z0 = lz4*4;
    const float* st = stats + b*144;
    const float invN = 1.0f/512000.0f;
    float* op = out + (size_t)b*COUT*VOX + (X0+lx)*SS + (Y0+ly)*SZ + (Z0+z0);

    float gate[12][4];
    #pragma unroll
    for (int g=0; g<6; ++g){
        __syncthreads();
        for (int l = tid; l < WG_FLOATS; l += 256) wl[l] = wg[g*WG_FLOATS + l];
        __syncthreads();

        float acc[12][4];
        conv_group(xs, wl, lx, ly, z0, acc);
        #pragma unroll
        for (int c12=0;c12<12;++c12){
            const int c = g*12 + c12;
            if (c < 28){
                float mean = st[c*2]*invN;
                float var  = fmaxf(st[c*2+1]*invN - mean*mean, 0.0f);
                float sw   = (1.0f/sqrtf(var+EPSF)) * bnw[c];
                float bb   = bnb[c];
                if (c < 16){
                    float4 o;
                    o.x = 1.41421356237f*fmaxf((acc[c12][0]-mean)*sw+bb, 0.0f);
                    o.y = 1.41421356237f*fmaxf((acc[c12][1]-mean)*sw+bb, 0.0f);
                    o.z = 1.41421356237f*fmaxf((acc[c12][2]-mean)*sw+bb, 0.0f);
                    o.w = 1.41421356237f*fmaxf((acc[c12][3]-mean)*sw+bb, 0.0f);
                    *reinterpret_cast<float4*>(op + (size_t)c*VOX) = o;
                } else {
                    #pragma unroll
                    for (int v=0;v<4;++v)
                        gate[c-16][v] = 1.8464f/(1.0f + expf(-((acc[c12][v]-mean)*sw+bb)));
                }
            } else if (c < 52){
                const int m = (c-28)/3;
                float n1 = (st[(28+3*m)*2+1]+st[(29+3*m)*2+1]+st[(30+3*m)*2+1])
                           * (1.0f/(3.0f*512000.0f));
                float sc = (1.0f/sqrtf(n1+EPSF)) * bnw[28+m];
                float4 o;
                o.x = acc[c12][0]*sc*gate[m][0]; o.y = acc[c12][1]*sc*gate[m][1];
                o.z = acc[c12][2]*sc*gate[m][2]; o.w = acc[c12][3]*sc*gate[m][3];
                *reinterpret_cast<float4*>(op + (size_t)(16 + (c-28))*VOX) = o;
            } else {
                const int m = (c-52)/5;
                float n2 = (st[(52+5*m)*2+1]+st[(53+5*m)*2+1]+st[(54+5*m)*2+1]
                          + st[(55+5*m)*2+1]+st[(56+5*m)*2+1]) * (1.0f/(5.0f*512000.0f));
                float sc = (1.0f/sqrtf(n2+EPSF)) * bnw[36+m];
                float4 o;
                o.x = acc[c12][0]*sc*gate[8+m][0]; o.y = acc[c12][1]*sc*gate[8+m][1];
                o.z = acc[c12][2]*sc*gate[8+m][2]; o.w = acc[c12][3]*sc*gate[8+m][3];
                *reinterpret_cast<float4*>(op + (size_t)(40 + (c-52))*VOX) = o;
            }
        }
    }
}

// ---------------------------------------------------------------------------
extern "C" void kernel_launch(void* const* d_in, const int* in_sizes, int n_in,
                              void* d_out, int out_size, void* d_ws, size_t ws_size,
                              hipStream_t stream)
{
    const float* x   = (const float*)d_in[0];
    const float* Wtp = (const float*)d_in[1];
    const float* bnw = (const float*)d_in[2];
    const float* bnb = (const float*)d_in[3];
    float* ws       = (float*)d_ws;
    float* wgt      = ws;                    // 7776 floats
    float* partials = ws + 8192;             // 1000*144 = 144000 floats
    float* stats    = ws + 8192 + 144000;    // 288 floats
    float* h        = ws + 160000;           // 2*72*512000 = 73,728,000 floats

    const size_t needH = (160000ull + 73728000ull) * 4ull;
    const bool useH = ws_size >= needH;

    k_build_weights<<<31, 256, 0, stream>>>(Wtp, wgt);
    k_conv_stats  <<<1000, 256, 0, stream>>>(x, wgt, partials, useH ? h : nullptr);
    k_reduce_stats<<<288, 256, 0, stream>>>(partials, stats);
    if (useH)
        k_norm_from_h<<<1000, 256, 0, stream>>>(h, stats, bnw, bnb, (float*)d_out);
    else
        k_conv_finish<<<1000, 256, 0, stream>>>(x, wgt, stats, bnw, bnb, (float*)d_out);
}

// Round 5
// 42.083 us; speedup vs baseline: 75.2495x; 9.5183x over previous
//
#include <hip/hip_runtime.h>
#include <math.h>

#define VOX 512000
#define COUT 60
#define F4_PER_CH (VOX/4)                  // 128000 float4 per channel
#define TOTAL_F4 (2u*COUT*F4_PER_CH)       // 15,360,000 float4 = 245.76 MB

// ---------------------------------------------------------------------------
// The reference's conv kernel is identically zero for ALL inputs (compile-time
// fact of the lattice geometry + radial window underflow in fp32; see proof in
// session journal / response). Hence h==0, instance-norm leaves bnb on the 28
// scalar channels, vector channels stay 0, and the gate yields:
//   out[b][c][vox] = sqrt(2)*relu(bnb[c])   for c < 16   (spatially constant)
//   out[b][c][vox] = 0                      for 16 <= c < 60
// This kernel constant-folds the whole operator into one write-only stream.
// ---------------------------------------------------------------------------
__global__ __launch_bounds__(256) void k_write_const(const float* __restrict__ bnb,
                                                     float4* __restrict__ out)
{
    __shared__ float val[COUT];
    if (threadIdx.x < COUT){
        float v = 0.0f;
        if (threadIdx.x < 16)
            v = 1.4142135623730951f * fmaxf(bnb[threadIdx.x], 0.0f);
        val[threadIdx.x] = v;
    }
    __syncthreads();

    const unsigned stride = gridDim.x * 256u;
    for (unsigned i = blockIdx.x*256u + threadIdx.x; i < TOTAL_F4; i += stride){
        // channel index: (i / 128000) % 60  (compiler strength-reduces the
        // constant division to mulhi+shift; ~4 VALU ops per 16B store)
        unsigned c = (i / (unsigned)F4_PER_CH) % (unsigned)COUT;
        float v = val[c];
        out[i] = make_float4(v, v, v, v);
    }
}

// ---------------------------------------------------------------------------
extern "C" void kernel_launch(void* const* d_in, const int* in_sizes, int n_in,
                              void* d_out, int out_size, void* d_ws, size_t ws_size,
                              hipStream_t stream)
{
    const float* bnb = (const float*)d_in[3];   // bn_bias (28 floats)
    // Memory-bound write-only stream: cap grid at ~2048 blocks, grid-stride.
    k_write_const<<<2048, 256, 0, stream>>>(bnb, (float4*)d_out);
}

// Round 6
// 35.765 us; speedup vs baseline: 88.5438x; 1.1767x over previous
//
#include <hip/hip_runtime.h>
#include <math.h>

#define VOX 512000
#define COUT 60
#define F4_PER_CH (VOX/4)      // 128000 float4 per (b,c) slab

// ---------------------------------------------------------------------------
// The reference's conv kernel is identically zero for ALL inputs (fp32
// underflow of the radial window at every lattice-tap norm — input-independent
// compile-time fact, verified over 5 rounds of full-pipeline computation at
// absmax 0.0). Hence h==0; instance-norm leaves bnb on scalar channels and the
// gate zeroes all vector channels:
//   out[b][c][:] = sqrt(2)*relu(bnb[c])  for c<16 ;  0  for 16<=c<60.
//
// Fill-kernel-shaped writer: per-block-uniform value (SGPR), contiguous
// dwordx4 stores, no per-store index math. blockIdx.y = b*60+c (120 slabs),
// blockIdx.x covers the 128000-float4 slab in 4-store chunks.
// ---------------------------------------------------------------------------
__global__ __launch_bounds__(256) void k_write_const(const float* __restrict__ bnb,
                                                     float4* __restrict__ out)
{
    const int bc = blockIdx.y;          // 0..119
    const int c  = bc % COUT;
    float v = 0.0f;
    if (c < 16) v = 1.4142135623730951f * fmaxf(bnb[c], 0.0f);  // uniform -> s_load
    const float4 q = make_float4(v, v, v, v);

    float4* p = out + (size_t)bc * F4_PER_CH
                    + (size_t)blockIdx.x * 1024 + threadIdx.x;
    p[0]   = q;
    p[256] = q;
    p[512] = q;
    p[768] = q;
}

// ---------------------------------------------------------------------------
extern "C" void kernel_launch(void* const* d_in, const int* in_sizes, int n_in,
                              void* d_out, int out_size, void* d_ws, size_t ws_size,
                              hipStream_t stream)
{
    const float* bnb = (const float*)d_in[3];   // bn_bias (28 floats)
    // 128000 float4 per slab / (256 threads * 4 stores) = 125 blocks.x ; 120 slabs
    dim3 grid(125, 120);
    k_write_const<<<grid, 256, 0, stream>>>(bnb, (float4*)d_out);
}